// Round 18
// baseline (82.584 us; speedup 1.0000x reference)
//
#include <hip/hip_runtime.h>

#define SS 4096
#define DD 1024
#define HH 16

typedef float nfloat4 __attribute__((ext_vector_type(4)));
typedef __attribute__((ext_vector_type(8))) short bf16x8;
typedef __attribute__((ext_vector_type(4))) float f32x4;

__device__ __forceinline__ short f2bf(float f) {
  union { float f; unsigned u; } z; z.f = f;
  return (short)((z.u + 0x8000u) >> 16);    // round-half-up to bf16
}

// ---------------------------------------------------------------------------
// K0: pre-pack wq,wk into MFMA A-fragment order, bf16.
// wf[m][st][lane][e] = w_m[st*32 + (lane>>4)*8 + e][lane&15]   (m: 0=q, 1=k)
// ---------------------------------------------------------------------------
__global__ __launch_bounds__(256) void k_wfrag(
    const float* __restrict__ wq, const float* __restrict__ wk,
    short* __restrict__ wf)
{
  const int m = blockIdx.x;
  const float* __restrict__ w = m ? wk : wq;
  short* __restrict__ dst = wf + m * 16384;
  for (int p = threadIdx.x; p < 2048; p += 256) {   // p = st*64 + lane
    const int t = p >> 6, l = p & 63;
    const int kbase = t*32 + ((l >> 4) * 8), col = l & 15;
    short v[8];
#pragma unroll
    for (int e = 0; e < 8; ++e)
      v[e] = f2bf(w[(size_t)(kbase + e)*HH + col]);
    short* o = dst + (size_t)p * 8;
#pragma unroll
    for (int e = 0; e < 8; ++e) o[e] = v[e];
  }
}

// ---------------------------------------------------------------------------
// K1: kh = sigmoid(k@wk+bk). REGISTER-staged (16 independent float4/thread,
// pinned by sched_barrier(0) -> 16KB/wave in flight, 4 blocks/CU), bf16
// converted into the swizzled LDS tile, MFMA 16x16x32. R16-proven (79.1us).
// Emits per-tile head-sums ksp[tile][16].
// ---------------------------------------------------------------------------
__global__ __launch_bounds__(256, 4) void k_kh(
    const float* __restrict__ k, const short* __restrict__ wf,
    const float* __restrict__ bk, float* __restrict__ kh,
    float* __restrict__ ksp)
{
  const int t = threadIdx.x;
  const int wid = t >> 6, lane = t & 63;
  const int s0 = blockIdx.x * 16;            // flat row over (B,S)
  const short* __restrict__ wfm = wf + 16384;   // k-half

  __shared__ short xs[16 * 1024];            // 32KB swizzled bf16 tile
  __shared__ float red[1024];                // 4KB partial-acc reduce

  float4 f[16];
  {
    const float* srow = k + (size_t)s0 * DD + t*4;
#pragma unroll
    for (int j = 0; j < 16; ++j)
      f[j] = *(const float4*)(srow + (size_t)j * DD);
  }
  const short* __restrict__ wfw = wfm + (size_t)(wid*8*64 + lane) * 8;
  bf16x8 afrag[8];
#pragma unroll
  for (int tt = 0; tt < 8; ++tt)
    afrag[tt] = *(const bf16x8*)(wfw + (size_t)(tt*64) * 8);
  __builtin_amdgcn_sched_barrier(0);         // pin: loads stay issued above

#pragma unroll
  for (int j = 0; j < 16; ++j) {
    short4 b4;
    b4.x = f2bf(f[j].x); b4.y = f2bf(f[j].y);
    b4.z = f2bf(f[j].z); b4.w = f2bf(f[j].w);
    const int colb = (t*8) ^ ((j & 7) << 4);
    *(short4*)((char*)xs + j*2048 + colb) = b4;
  }
  __syncthreads();

  const int row = lane & 15, g = lane >> 4;
  const char* __restrict__ xrow = (const char*)xs + row*2048;
  f32x4 acc = {0.f, 0.f, 0.f, 0.f};
#pragma unroll
  for (int tt = 0; tt < 8; ++tt) {
    const int colb = ((wid*256 + tt*32 + g*8) * 2) ^ ((row & 7) << 4);
    const bf16x8 bb = *(const bf16x8*)(xrow + colb);
    acc = __builtin_amdgcn_mfma_f32_16x16x32_bf16(afrag[tt], bb, acc, 0, 0, 0);
  }
  *(f32x4*)&red[(wid*64 + lane)*4] = acc;
  __syncthreads();
  const int orow = t >> 4, ohead = t & 15;
  const int lane2 = ((ohead >> 2) << 4) + orow;
  const int j = ohead & 3;
  const float sacc = red[0*256 + lane2*4 + j] + red[1*256 + lane2*4 + j]
                   + red[2*256 + lane2*4 + j] + red[3*256 + lane2*4 + j];
  const float sig = 1.f/(1.f + __expf(-(sacc + bk[ohead])));
  kh[(size_t)(s0 + orow)*HH + ohead] = sig;
  __syncthreads();                           // red reads done
  red[t] = sig;
  __syncthreads();
  if (t < 16) {
    float s = 0.f;
#pragma unroll
    for (int r = 0; r < 16; ++r) s += red[r*16 + t];
    ksp[blockIdx.x*16 + t] = s;
  }
}

// ---------------------------------------------------------------------------
// K2: kvT partials. CHANGED: 64 s-chunks (2048 blocks = 8 blocks/CU, 2x the
// in-flight v-reads of the 32-chunk version). Block covers 64 rows; row
// mapping s = (jj*4+g)*64 + schunk keeps concurrent reads on consecutive
// rows. Partials (16 MB) -> d_out scratch. (R8-proven body.)
// ---------------------------------------------------------------------------
__global__ __launch_bounds__(256, 8) void k_kvt(
    const float* __restrict__ v, const float* __restrict__ kh,
    float* __restrict__ part)
{
  const int schunk = blockIdx.x;   // 0..63
  const int dchunk = blockIdx.y;   // 0..7
  const int b = blockIdx.z;
  const int t = threadIdx.x;
  const int c = t & 31;
  const int hh2 = (t >> 5) & 1;
  const int g = t >> 6;            // 0..3
  const int d0 = dchunk*128 + c*4;
  float acc[8][4];
#pragma unroll
  for (int h = 0; h < 8; ++h) {
    acc[h][0] = 0.f; acc[h][1] = 0.f; acc[h][2] = 0.f; acc[h][3] = 0.f;
  }
#pragma unroll 2
  for (int jj = 0; jj < 16; ++jj) {
    const int s = (jj*4 + g)*64 + schunk;
    const size_t rb = (size_t)(b*SS + s);
    const float4 v4 = *(const float4*)(v + rb*DD + d0);
    const float4* khp = (const float4*)(kh + rb*HH) + hh2*2;
    const float4 k0 = khp[0], k1 = khp[1];
    const float kk[8] = {k0.x,k0.y,k0.z,k0.w, k1.x,k1.y,k1.z,k1.w};
#pragma unroll
    for (int h = 0; h < 8; ++h) {
      acc[h][0] = fmaf(kk[h], v4.x, acc[h][0]);
      acc[h][1] = fmaf(kk[h], v4.y, acc[h][1]);
      acc[h][2] = fmaf(kk[h], v4.z, acc[h][2]);
      acc[h][3] = fmaf(kk[h], v4.w, acc[h][3]);
    }
  }
  __shared__ float lds[4][2][128];
  const size_t pbase = (size_t)((b*8 + dchunk)*64 + schunk) * 2048;
#pragma unroll   // full unroll: acc indices stay compile-time
  for (int h = 0; h < 8; ++h) {
    *(float4*)&lds[g][hh2][c*4] =
        make_float4(acc[h][0], acc[h][1], acc[h][2], acc[h][3]);
    __syncthreads();
    {
      const int hh2r = t >> 7, dl = t & 127;
      const float sum = lds[0][hh2r][dl] + lds[1][hh2r][dl]
                      + lds[2][hh2r][dl] + lds[3][hh2r][dl];
      part[pbase + (hh2r*8 + h)*128 + dl] = sum;
    }
    __syncthreads();
  }
}

// ---------------------------------------------------------------------------
// K3: reduce part over 64 schunks -> kvt[b][h][1024]. 128 blocks, coalesced.
// ---------------------------------------------------------------------------
__global__ __launch_bounds__(256, 8) void k_red(
    const float* __restrict__ part, float* __restrict__ kvt)
{
  const int dchunk = blockIdx.x;
  const int b = blockIdx.y;
  const int hq = blockIdx.z;       // 0..3
  const int t = threadIdx.x;
  const size_t pb = (size_t)((b*8 + dchunk)*64) * 2048;
#pragma unroll
  for (int ho = 0; ho < 2; ++ho) {
    const int h = hq*4 + ho*2 + (t >> 7), dl = t & 127;
    float s = 0.f;
#pragma unroll 8
    for (int sc = 0; sc < 64; ++sc)
      s += part[pb + (size_t)sc*2048 + h*128 + dl];
    kvt[(size_t)(b*16 + h)*1024 + dchunk*128 + dl] = s;
  }
}

// ---------------------------------------------------------------------------
// K4: wv contraction, coalesced + parallel (verbatim R12). Grid (16,4,4).
// ---------------------------------------------------------------------------
__global__ __launch_bounds__(256, 4) void k_kv(
    const float* __restrict__ kvt, const float* __restrict__ wv,
    float* __restrict__ kvp)
{
  const int h = blockIdx.x;    // 0..15
  const int b = blockIdx.y;    // 0..3
  const int dq = blockIdx.z;   // 0..3
  const int t = threadIdx.x;
  const int w = t >> 6, lane = t & 63;
  __shared__ float kvs[256];
  __shared__ float red[256];
  kvs[t] = kvt[(size_t)(b*16 + h)*1024 + dq*256 + t];
  __syncthreads();
  const float* __restrict__ wp = wv + (size_t)(dq*256 + w*64)*DD + h*64 + lane;
  float acc = 0.f;
#pragma unroll 16
  for (int i = 0; i < 64; ++i)
    acc = fmaf(kvs[w*64 + i], wp[(size_t)i*DD], acc);
  red[t] = acc;
  __syncthreads();
  if (t < 64)
    kvp[((size_t)(b*16 + h)*4 + dq)*64 + t] =
        red[t] + red[64+t] + red[128+t] + red[192+t];
}

// ---------------------------------------------------------------------------
// K5: finalize kv (verbatim R12). Grid (4 b).
// ---------------------------------------------------------------------------
__global__ __launch_bounds__(256) void k_kvfin(
    const float* __restrict__ kvp, const float* __restrict__ ksp,
    const float* __restrict__ bv, float* __restrict__ kv)
{
  const int b = blockIdx.x;
  const int t = threadIdx.x;
  __shared__ float red[256];
  __shared__ float ksum[16];
  float s = 0.f;
#pragma unroll
  for (int m = 0; m < 16; ++m)
    s += ksp[b*4096 + m*256 + t];
  red[t] = s;
  __syncthreads();
  if (t < 16) {
    float ks = 0.f;
#pragma unroll
    for (int g = 0; g < 16; ++g) ks += red[g*16 + t];
    ksum[t] = ks;
  }
  __syncthreads();
#pragma unroll
  for (int j = 0; j < 4; ++j) {
    const int idx = j*256 + t;
    const int h = idx >> 6;
    const float* kp = kvp + (size_t)(b*16 + h)*256 + (idx & 63);
    kv[(size_t)b*1024 + idx] =
        kp[0] + kp[64] + kp[128] + kp[192] + ksum[h]*bv[idx];
  }
}

// ---------------------------------------------------------------------------
// K6: per (b,h): state = cumsum_h kv, then W2 = state @ wo rows (verbatim
// R12). Grid 64.
// ---------------------------------------------------------------------------
__global__ __launch_bounds__(256) void k_w2(
    const float* __restrict__ kv, const float* __restrict__ wo,
    float* __restrict__ W2)
{
  const int bh = blockIdx.x;
  const int b = bh >> 4, h = bh & 15;
  const int t = threadIdx.x;
  __shared__ float st[64];
  if (t < 64) {
    float s = 0.f;
    for (int hp = 0; hp <= h; ++hp) s += kv[(size_t)b*1024 + hp*64 + t];
    st[t] = s;
  }
  __syncthreads();
  const int d0 = t * 4;
  float4 acc = {0.f, 0.f, 0.f, 0.f};
#pragma unroll 4
  for (int dv = 0; dv < 64; ++dv) {
    const float sv = st[dv];
    const float4 w4 = *(const float4*)(wo + (size_t)(h*64 + dv)*DD + d0);
    acc.x = fmaf(sv, w4.x, acc.x);
    acc.y = fmaf(sv, w4.y, acc.y);
    acc.z = fmaf(sv, w4.z, acc.z);
    acc.w = fmaf(sv, w4.w, acc.w);
  }
  *(float4*)(W2 + (size_t)(b*HH + h)*DD + d0) = acc;
}

// ---------------------------------------------------------------------------
// K7: FUSED q-projection + output (R16-proven). Register-staged pinned
// loads, swizzled bf16 LDS, MFMA; W2/bo loaded after MFMA; nontemporal
// stores. 4 blocks/CU.
// ---------------------------------------------------------------------------
__global__ __launch_bounds__(256, 4) void k_qout(
    const float* __restrict__ q, const short* __restrict__ wf,
    const float* __restrict__ bq, const float* __restrict__ W2,
    const float* __restrict__ bo, float* __restrict__ out)
{
  const int t = threadIdx.x;
  const int wid = t >> 6, lane = t & 63;
  const int tile = blockIdx.x;               // 0..1023
  const int b = tile >> 8;                   // 256 tiles per batch
  const int s0 = tile * 16;

  __shared__ short xs[16 * 1024];            // 32KB swizzled bf16 tile
  __shared__ float red[1024];                // 4KB
  __shared__ float qs[256];                  // 1KB qh tile

  float4 f[16];
  {
    const float* srow = q + (size_t)s0 * DD + t*4;
#pragma unroll
    for (int j = 0; j < 16; ++j)
      f[j] = *(const float4*)(srow + (size_t)j * DD);
  }
  const short* __restrict__ wfw = wf + (size_t)(wid*8*64 + lane) * 8;  // q-half
  bf16x8 afrag[8];
#pragma unroll
  for (int tt = 0; tt < 8; ++tt)
    afrag[tt] = *(const bf16x8*)(wfw + (size_t)(tt*64) * 8);
  __builtin_amdgcn_sched_barrier(0);         // pin loads above

#pragma unroll
  for (int j = 0; j < 16; ++j) {
    short4 b4;
    b4.x = f2bf(f[j].x); b4.y = f2bf(f[j].y);
    b4.z = f2bf(f[j].z); b4.w = f2bf(f[j].w);
    const int colb = (t*8) ^ ((j & 7) << 4);
    *(short4*)((char*)xs + j*2048 + colb) = b4;
  }
  __syncthreads();

  const int row = lane & 15, g = lane >> 4;
  const char* __restrict__ xrow = (const char*)xs + row*2048;
  f32x4 acc = {0.f, 0.f, 0.f, 0.f};
#pragma unroll
  for (int tt = 0; tt < 8; ++tt) {
    const int colb = ((wid*256 + tt*32 + g*8) * 2) ^ ((row & 7) << 4);
    const bf16x8 bb = *(const bf16x8*)(xrow + colb);
    acc = __builtin_amdgcn_mfma_f32_16x16x32_bf16(afrag[tt], bb, acc, 0, 0, 0);
  }
  *(f32x4*)&red[(wid*64 + lane)*4] = acc;
  __syncthreads();
  {
    const int orow = t >> 4, ohead = t & 15;
    const int lane2 = ((ohead >> 2) << 4) + orow;
    const int j = ohead & 3;
    const float sacc = red[0*256 + lane2*4 + j] + red[1*256 + lane2*4 + j]
                     + red[2*256 + lane2*4 + j] + red[3*256 + lane2*4 + j];
    const float val = sacc + bq[ohead];
    qs[orow*16 + ohead] = 1.f/(1.f + __expf(-val));
  }
  __syncthreads();

  // W2/bo loads here: staging regs are dead, peak VGPR stays low; latency
  // hidden by the other 3 co-resident blocks.
  float4 w2[16];
  {
    const float* w2p = W2 + (size_t)(b*HH)*DD + t*4;
#pragma unroll
    for (int h = 0; h < 16; ++h) w2[h] = *(const float4*)(w2p + h*DD);
  }
  const float4 bo4 = *(const float4*)(bo + t*4);

#pragma unroll
  for (int r = 0; r < 16; ++r) {
    float4 o = bo4;
#pragma unroll
    for (int h = 0; h < 16; ++h) {
      const float qv = qs[r*16 + h];
      o.x = fmaf(qv, w2[h].x, o.x);
      o.y = fmaf(qv, w2[h].y, o.y);
      o.z = fmaf(qv, w2[h].z, o.z);
      o.w = fmaf(qv, w2[h].w, o.w);
    }
    nfloat4 ov = { o.x, o.y, o.z, o.w };
    nfloat4* dst = (nfloat4*)(out + (size_t)(s0 + r)*DD + t*4);
    __builtin_nontemporal_store(ov, dst);
  }
}

// ---------------------------------------------------------------------------
extern "C" void kernel_launch(void* const* d_in, const int* in_sizes, int n_in,
                              void* d_out, int out_size, void* d_ws, size_t ws_size,
                              hipStream_t stream)
{
  const float* q  = (const float*)d_in[0];
  const float* k  = (const float*)d_in[1];
  const float* v  = (const float*)d_in[2];
  const float* wq = (const float*)d_in[3];
  const float* bq = (const float*)d_in[4];
  const float* wk = (const float*)d_in[5];
  const float* bk = (const float*)d_in[6];
  const float* wv = (const float*)d_in[7];
  const float* bv = (const float*)d_in[8];
  const float* wo = (const float*)d_in[9];
  const float* bo = (const float*)d_in[10];
  float* out = (float*)d_out;
  float* ws  = (float*)d_ws;

  // ws layout (floats):
  // kh 262144 | kvt 65536 | kvp 16384 | ksp 16384 | kv 4096 | W2 65536 | wf
  float* kh  = ws;
  float* kvt = ws + 262144;
  float* kvp = ws + 327680;
  float* ksp = ws + 344064;
  float* kv  = ws + 360448;
  float* W2  = ws + 364544;
  short* wf  = (short*)(ws + 430080);
  // part (16 MB: 2048 blocks * 2048 floats) at the FRONT of d_out: consumed
  // by k_red, fully overwritten by k_qout afterwards.
  float* part = out;

  hipLaunchKernelGGL(k_wfrag, dim3(2), dim3(256), 0, stream,
                     wq, wk, wf);
  hipLaunchKernelGGL(k_kh, dim3(1024), dim3(256), 0, stream,
                     k, wf, bk, kh, ksp);
  hipLaunchKernelGGL(k_kvt, dim3(64, 8, 4), dim3(256), 0, stream,
                     v, kh, part);
  hipLaunchKernelGGL(k_red, dim3(8, 4, 4), dim3(256), 0, stream,
                     part, kvt);
  hipLaunchKernelGGL(k_kv, dim3(16, 4, 4), dim3(256), 0, stream,
                     kvt, wv, kvp);
  hipLaunchKernelGGL(k_kvfin, dim3(4), dim3(256), 0, stream,
                     kvp, ksp, bv, kv);
  hipLaunchKernelGGL(k_w2, dim3(64), dim3(256), 0, stream,
                     kv, wo, W2);
  hipLaunchKernelGGL(k_qout, dim3(1024), dim3(256), 0, stream,
                     q, wf, bq, W2, bo, out);
}

// Round 19
// 79.120 us; speedup vs baseline: 1.0438x; 1.0438x over previous
//
#include <hip/hip_runtime.h>

#define SS 4096
#define DD 1024
#define HH 16

typedef float nfloat4 __attribute__((ext_vector_type(4)));
typedef __attribute__((ext_vector_type(8))) short bf16x8;
typedef __attribute__((ext_vector_type(4))) float f32x4;

__device__ __forceinline__ short f2bf(float f) {
  union { float f; unsigned u; } z; z.f = f;
  return (short)((z.u + 0x8000u) >> 16);    // round-half-up to bf16
}

// ---------------------------------------------------------------------------
// K0: pre-pack wq,wk into MFMA A-fragment order, bf16.
// wf[m][st][lane][e] = w_m[st*32 + (lane>>4)*8 + e][lane&15]   (m: 0=q, 1=k)
// ---------------------------------------------------------------------------
__global__ __launch_bounds__(256) void k_wfrag(
    const float* __restrict__ wq, const float* __restrict__ wk,
    short* __restrict__ wf)
{
  const int m = blockIdx.x;
  const float* __restrict__ w = m ? wk : wq;
  short* __restrict__ dst = wf + m * 16384;
  for (int p = threadIdx.x; p < 2048; p += 256) {   // p = st*64 + lane
    const int t = p >> 6, l = p & 63;
    const int kbase = t*32 + ((l >> 4) * 8), col = l & 15;
    short v[8];
#pragma unroll
    for (int e = 0; e < 8; ++e)
      v[e] = f2bf(w[(size_t)(kbase + e)*HH + col]);
    short* o = dst + (size_t)p * 8;
#pragma unroll
    for (int e = 0; e < 8; ++e) o[e] = v[e];
  }
}

// ---------------------------------------------------------------------------
// K1: kh = sigmoid(k@wk+bk). REGISTER-staged (16 independent float4/thread,
// pinned by sched_barrier(0) -> 16KB/wave in flight, 4 blocks/CU), bf16
// converted into the swizzled LDS tile, MFMA 16x16x32. R16-proven (79.1us).
// Emits per-tile head-sums ksp[tile][16].
// ---------------------------------------------------------------------------
__global__ __launch_bounds__(256, 4) void k_kh(
    const float* __restrict__ k, const short* __restrict__ wf,
    const float* __restrict__ bk, float* __restrict__ kh,
    float* __restrict__ ksp)
{
  const int t = threadIdx.x;
  const int wid = t >> 6, lane = t & 63;
  const int s0 = blockIdx.x * 16;            // flat row over (B,S)
  const short* __restrict__ wfm = wf + 16384;   // k-half

  __shared__ short xs[16 * 1024];            // 32KB swizzled bf16 tile
  __shared__ float red[1024];                // 4KB partial-acc reduce

  float4 f[16];
  {
    const float* srow = k + (size_t)s0 * DD + t*4;
#pragma unroll
    for (int j = 0; j < 16; ++j)
      f[j] = *(const float4*)(srow + (size_t)j * DD);
  }
  const short* __restrict__ wfw = wfm + (size_t)(wid*8*64 + lane) * 8;
  bf16x8 afrag[8];
#pragma unroll
  for (int tt = 0; tt < 8; ++tt)
    afrag[tt] = *(const bf16x8*)(wfw + (size_t)(tt*64) * 8);
  __builtin_amdgcn_sched_barrier(0);         // pin: loads stay issued above

#pragma unroll
  for (int j = 0; j < 16; ++j) {
    short4 b4;
    b4.x = f2bf(f[j].x); b4.y = f2bf(f[j].y);
    b4.z = f2bf(f[j].z); b4.w = f2bf(f[j].w);
    const int colb = (t*8) ^ ((j & 7) << 4);
    *(short4*)((char*)xs + j*2048 + colb) = b4;
  }
  __syncthreads();

  const int row = lane & 15, g = lane >> 4;
  const char* __restrict__ xrow = (const char*)xs + row*2048;
  f32x4 acc = {0.f, 0.f, 0.f, 0.f};
#pragma unroll
  for (int tt = 0; tt < 8; ++tt) {
    const int colb = ((wid*256 + tt*32 + g*8) * 2) ^ ((row & 7) << 4);
    const bf16x8 bb = *(const bf16x8*)(xrow + colb);
    acc = __builtin_amdgcn_mfma_f32_16x16x32_bf16(afrag[tt], bb, acc, 0, 0, 0);
  }
  *(f32x4*)&red[(wid*64 + lane)*4] = acc;
  __syncthreads();
  const int orow = t >> 4, ohead = t & 15;
  const int lane2 = ((ohead >> 2) << 4) + orow;
  const int j = ohead & 3;
  const float sacc = red[0*256 + lane2*4 + j] + red[1*256 + lane2*4 + j]
                   + red[2*256 + lane2*4 + j] + red[3*256 + lane2*4 + j];
  const float sig = 1.f/(1.f + __expf(-(sacc + bk[ohead])));
  kh[(size_t)(s0 + orow)*HH + ohead] = sig;
  __syncthreads();                           // red reads done
  red[t] = sig;
  __syncthreads();
  if (t < 16) {
    float s = 0.f;
#pragma unroll
    for (int r = 0; r < 16; ++r) s += red[r*16 + t];
    ksp[blockIdx.x*16 + t] = s;
  }
}

// ---------------------------------------------------------------------------
// K2: kvT partials (R16 config: 32 s-chunks, 1024 blocks, 8 blocks/CU).
// Row mapping s = (jj*4+g)*32 + schunk. Partials (8 MB) -> d_out scratch.
// ---------------------------------------------------------------------------
__global__ __launch_bounds__(256, 8) void k_kvt(
    const float* __restrict__ v, const float* __restrict__ kh,
    float* __restrict__ part)
{
  const int schunk = blockIdx.x;   // 0..31
  const int dchunk = blockIdx.y;   // 0..7
  const int b = blockIdx.z;
  const int t = threadIdx.x;
  const int c = t & 31;
  const int hh2 = (t >> 5) & 1;
  const int g = t >> 6;            // 0..3
  const int d0 = dchunk*128 + c*4;
  float acc[8][4];
#pragma unroll
  for (int h = 0; h < 8; ++h) {
    acc[h][0] = 0.f; acc[h][1] = 0.f; acc[h][2] = 0.f; acc[h][3] = 0.f;
  }
#pragma unroll 2
  for (int jj = 0; jj < 32; ++jj) {
    const int s = (jj*4 + g)*32 + schunk;
    const size_t rb = (size_t)(b*SS + s);
    const float4 v4 = *(const float4*)(v + rb*DD + d0);
    const float4* khp = (const float4*)(kh + rb*HH) + hh2*2;
    const float4 k0 = khp[0], k1 = khp[1];
    const float kk[8] = {k0.x,k0.y,k0.z,k0.w, k1.x,k1.y,k1.z,k1.w};
#pragma unroll
    for (int h = 0; h < 8; ++h) {
      acc[h][0] = fmaf(kk[h], v4.x, acc[h][0]);
      acc[h][1] = fmaf(kk[h], v4.y, acc[h][1]);
      acc[h][2] = fmaf(kk[h], v4.z, acc[h][2]);
      acc[h][3] = fmaf(kk[h], v4.w, acc[h][3]);
    }
  }
  __shared__ float lds[4][2][128];
  const size_t pbase = (size_t)((b*8 + dchunk)*32 + schunk) * 2048;
#pragma unroll   // full unroll: acc indices stay compile-time
  for (int h = 0; h < 8; ++h) {
    *(float4*)&lds[g][hh2][c*4] =
        make_float4(acc[h][0], acc[h][1], acc[h][2], acc[h][3]);
    __syncthreads();
    {
      const int hh2r = t >> 7, dl = t & 127;
      const float sum = lds[0][hh2r][dl] + lds[1][hh2r][dl]
                      + lds[2][hh2r][dl] + lds[3][hh2r][dl];
      part[pbase + (hh2r*8 + h)*128 + dl] = sum;
    }
    __syncthreads();
  }
}

// ---------------------------------------------------------------------------
// K3: reduce part over 32 schunks -> kvt[b][h][1024]. 128 blocks, coalesced.
// ---------------------------------------------------------------------------
__global__ __launch_bounds__(256, 8) void k_red(
    const float* __restrict__ part, float* __restrict__ kvt)
{
  const int dchunk = blockIdx.x;
  const int b = blockIdx.y;
  const int hq = blockIdx.z;       // 0..3
  const int t = threadIdx.x;
  const size_t pb = (size_t)((b*8 + dchunk)*32) * 2048;
#pragma unroll
  for (int ho = 0; ho < 2; ++ho) {
    const int h = hq*4 + ho*2 + (t >> 7), dl = t & 127;
    float s = 0.f;
#pragma unroll 8
    for (int sc = 0; sc < 32; ++sc)
      s += part[pb + (size_t)sc*2048 + h*128 + dl];
    kvt[(size_t)(b*16 + h)*1024 + dchunk*128 + dl] = s;
  }
}

// ---------------------------------------------------------------------------
// K4: wv contraction, coalesced + parallel (verbatim R12). Grid (16,4,4).
// ---------------------------------------------------------------------------
__global__ __launch_bounds__(256, 4) void k_kv(
    const float* __restrict__ kvt, const float* __restrict__ wv,
    float* __restrict__ kvp)
{
  const int h = blockIdx.x;    // 0..15
  const int b = blockIdx.y;    // 0..3
  const int dq = blockIdx.z;   // 0..3
  const int t = threadIdx.x;
  const int w = t >> 6, lane = t & 63;
  __shared__ float kvs[256];
  __shared__ float red[256];
  kvs[t] = kvt[(size_t)(b*16 + h)*1024 + dq*256 + t];
  __syncthreads();
  const float* __restrict__ wp = wv + (size_t)(dq*256 + w*64)*DD + h*64 + lane;
  float acc = 0.f;
#pragma unroll 16
  for (int i = 0; i < 64; ++i)
    acc = fmaf(kvs[w*64 + i], wp[(size_t)i*DD], acc);
  red[t] = acc;
  __syncthreads();
  if (t < 64)
    kvp[((size_t)(b*16 + h)*4 + dq)*64 + t] =
        red[t] + red[64+t] + red[128+t] + red[192+t];
}

// ---------------------------------------------------------------------------
// K5: finalize kv (verbatim R12). Grid (4 b).
// ---------------------------------------------------------------------------
__global__ __launch_bounds__(256) void k_kvfin(
    const float* __restrict__ kvp, const float* __restrict__ ksp,
    const float* __restrict__ bv, float* __restrict__ kv)
{
  const int b = blockIdx.x;
  const int t = threadIdx.x;
  __shared__ float red[256];
  __shared__ float ksum[16];
  float s = 0.f;
#pragma unroll
  for (int m = 0; m < 16; ++m)
    s += ksp[b*4096 + m*256 + t];
  red[t] = s;
  __syncthreads();
  if (t < 16) {
    float ks = 0.f;
#pragma unroll
    for (int g = 0; g < 16; ++g) ks += red[g*16 + t];
    ksum[t] = ks;
  }
  __syncthreads();
#pragma unroll
  for (int j = 0; j < 4; ++j) {
    const int idx = j*256 + t;
    const int h = idx >> 6;
    const float* kp = kvp + (size_t)(b*16 + h)*256 + (idx & 63);
    kv[(size_t)b*1024 + idx] =
        kp[0] + kp[64] + kp[128] + kp[192] + ksum[h]*bv[idx];
  }
}

// ---------------------------------------------------------------------------
// K6: per (b,h): state = cumsum_h kv, then W2 = state @ wo rows (verbatim
// R12). Grid 64.
// ---------------------------------------------------------------------------
__global__ __launch_bounds__(256) void k_w2(
    const float* __restrict__ kv, const float* __restrict__ wo,
    float* __restrict__ W2)
{
  const int bh = blockIdx.x;
  const int b = bh >> 4, h = bh & 15;
  const int t = threadIdx.x;
  __shared__ float st[64];
  if (t < 64) {
    float s = 0.f;
    for (int hp = 0; hp <= h; ++hp) s += kv[(size_t)b*1024 + hp*64 + t];
    st[t] = s;
  }
  __syncthreads();
  const int d0 = t * 4;
  float4 acc = {0.f, 0.f, 0.f, 0.f};
#pragma unroll 4
  for (int dv = 0; dv < 64; ++dv) {
    const float sv = st[dv];
    const float4 w4 = *(const float4*)(wo + (size_t)(h*64 + dv)*DD + d0);
    acc.x = fmaf(sv, w4.x, acc.x);
    acc.y = fmaf(sv, w4.y, acc.y);
    acc.z = fmaf(sv, w4.z, acc.z);
    acc.w = fmaf(sv, w4.w, acc.w);
  }
  *(float4*)(W2 + (size_t)(b*HH + h)*DD + d0) = acc;
}

// ---------------------------------------------------------------------------
// K7: FUSED q-projection + output (R16-proven). Register-staged pinned
// loads, swizzled bf16 LDS, MFMA; W2/bo loaded after MFMA; nontemporal
// stores. 4 blocks/CU.
// ---------------------------------------------------------------------------
__global__ __launch_bounds__(256, 4) void k_qout(
    const float* __restrict__ q, const short* __restrict__ wf,
    const float* __restrict__ bq, const float* __restrict__ W2,
    const float* __restrict__ bo, float* __restrict__ out)
{
  const int t = threadIdx.x;
  const int wid = t >> 6, lane = t & 63;
  const int tile = blockIdx.x;               // 0..1023
  const int b = tile >> 8;                   // 256 tiles per batch
  const int s0 = tile * 16;

  __shared__ short xs[16 * 1024];            // 32KB swizzled bf16 tile
  __shared__ float red[1024];                // 4KB
  __shared__ float qs[256];                  // 1KB qh tile

  float4 f[16];
  {
    const float* srow = q + (size_t)s0 * DD + t*4;
#pragma unroll
    for (int j = 0; j < 16; ++j)
      f[j] = *(const float4*)(srow + (size_t)j * DD);
  }
  const short* __restrict__ wfw = wf + (size_t)(wid*8*64 + lane) * 8;  // q-half
  bf16x8 afrag[8];
#pragma unroll
  for (int tt = 0; tt < 8; ++tt)
    afrag[tt] = *(const bf16x8*)(wfw + (size_t)(tt*64) * 8);
  __builtin_amdgcn_sched_barrier(0);         // pin loads above

#pragma unroll
  for (int j = 0; j < 16; ++j) {
    short4 b4;
    b4.x = f2bf(f[j].x); b4.y = f2bf(f[j].y);
    b4.z = f2bf(f[j].z); b4.w = f2bf(f[j].w);
    const int colb = (t*8) ^ ((j & 7) << 4);
    *(short4*)((char*)xs + j*2048 + colb) = b4;
  }
  __syncthreads();

  const int row = lane & 15, g = lane >> 4;
  const char* __restrict__ xrow = (const char*)xs + row*2048;
  f32x4 acc = {0.f, 0.f, 0.f, 0.f};
#pragma unroll
  for (int tt = 0; tt < 8; ++tt) {
    const int colb = ((wid*256 + tt*32 + g*8) * 2) ^ ((row & 7) << 4);
    const bf16x8 bb = *(const bf16x8*)(xrow + colb);
    acc = __builtin_amdgcn_mfma_f32_16x16x32_bf16(afrag[tt], bb, acc, 0, 0, 0);
  }
  *(f32x4*)&red[(wid*64 + lane)*4] = acc;
  __syncthreads();
  {
    const int orow = t >> 4, ohead = t & 15;
    const int lane2 = ((ohead >> 2) << 4) + orow;
    const int j = ohead & 3;
    const float sacc = red[0*256 + lane2*4 + j] + red[1*256 + lane2*4 + j]
                     + red[2*256 + lane2*4 + j] + red[3*256 + lane2*4 + j];
    const float val = sacc + bq[ohead];
    qs[orow*16 + ohead] = 1.f/(1.f + __expf(-val));
  }
  __syncthreads();

  // W2/bo loads here: staging regs are dead, peak VGPR stays low; latency
  // hidden by the other 3 co-resident blocks.
  float4 w2[16];
  {
    const float* w2p = W2 + (size_t)(b*HH)*DD + t*4;
#pragma unroll
    for (int h = 0; h < 16; ++h) w2[h] = *(const float4*)(w2p + h*DD);
  }
  const float4 bo4 = *(const float4*)(bo + t*4);

#pragma unroll
  for (int r = 0; r < 16; ++r) {
    float4 o = bo4;
#pragma unroll
    for (int h = 0; h < 16; ++h) {
      const float qv = qs[r*16 + h];
      o.x = fmaf(qv, w2[h].x, o.x);
      o.y = fmaf(qv, w2[h].y, o.y);
      o.z = fmaf(qv, w2[h].z, o.z);
      o.w = fmaf(qv, w2[h].w, o.w);
    }
    nfloat4 ov = { o.x, o.y, o.z, o.w };
    nfloat4* dst = (nfloat4*)(out + (size_t)(s0 + r)*DD + t*4);
    __builtin_nontemporal_store(ov, dst);
  }
}

// ---------------------------------------------------------------------------
extern "C" void kernel_launch(void* const* d_in, const int* in_sizes, int n_in,
                              void* d_out, int out_size, void* d_ws, size_t ws_size,
                              hipStream_t stream)
{
  const float* q  = (const float*)d_in[0];
  const float* k  = (const float*)d_in[1];
  const float* v  = (const float*)d_in[2];
  const float* wq = (const float*)d_in[3];
  const float* bq = (const float*)d_in[4];
  const float* wk = (const float*)d_in[5];
  const float* bk = (const float*)d_in[6];
  const float* wv = (const float*)d_in[7];
  const float* bv = (const float*)d_in[8];
  const float* wo = (const float*)d_in[9];
  const float* bo = (const float*)d_in[10];
  float* out = (float*)d_out;
  float* ws  = (float*)d_ws;

  // ws layout (floats):
  // kh 262144 | kvt 65536 | kvp 16384 | ksp 16384 | kv 4096 | W2 65536 | wf
  float* kh  = ws;
  float* kvt = ws + 262144;
  float* kvp = ws + 327680;
  float* ksp = ws + 344064;
  float* kv  = ws + 360448;
  float* W2  = ws + 364544;
  short* wf  = (short*)(ws + 430080);
  // part (8 MB) at the FRONT of d_out: consumed by k_red, fully overwritten
  // by k_qout afterwards.
  float* part = out;

  hipLaunchKernelGGL(k_wfrag, dim3(2), dim3(256), 0, stream,
                     wq, wk, wf);
  hipLaunchKernelGGL(k_kh, dim3(1024), dim3(256), 0, stream,
                     k, wf, bk, kh, ksp);
  hipLaunchKernelGGL(k_kvt, dim3(32, 8, 4), dim3(256), 0, stream,
                     v, kh, part);
  hipLaunchKernelGGL(k_red, dim3(8, 4, 4), dim3(256), 0, stream,
                     part, kvt);
  hipLaunchKernelGGL(k_kv, dim3(16, 4, 4), dim3(256), 0, stream,
                     kvt, wv, kvp);
  hipLaunchKernelGGL(k_kvfin, dim3(4), dim3(256), 0, stream,
                     kvp, ksp, bv, kv);
  hipLaunchKernelGGL(k_w2, dim3(64), dim3(256), 0, stream,
                     kv, wo, W2);
  hipLaunchKernelGGL(k_qout, dim3(1024), dim3(256), 0, stream,
                     q, wf, bq, W2, bo, out);
}